// Round 12
// baseline (91.006 us; speedup 1.0000x reference)
//
#include <hip/hip_runtime.h>
#include <stdint.h>

#define NPTS 8192
#define BLK 512                       // 8 waves
#define QPB 32                        // queries per block (one MFMA row-block)
#define GRPS 256                      // query groups per batch (8192/32)
// main grid: B * GRPS * 2 (candidate halves); finish grid: B * GRPS

typedef __attribute__((ext_vector_type(8)))  short short8;
typedef __attribute__((ext_vector_type(16))) float float16;

__device__ __forceinline__ uint32_t umin32(uint32_t a, uint32_t b) { return a < b ? a : b; }
__device__ __forceinline__ uint32_t umax32(uint32_t a, uint32_t b) { return a > b ? a : b; }

__device__ __forceinline__ void ins3(uint32_t key, uint32_t& k0, uint32_t& k1, uint32_t& k2) {
    uint32_t a = umin32(k0, key);
    uint32_t b = umax32(k0, key);
    k0 = a;
    uint32_t c = umin32(k1, b);
    uint32_t d = umax32(k1, b);
    k1 = c;
    k2 = umin32(k2, d);
}

// RNE float->bf16 (bits in uint16) and back.
__device__ __forceinline__ uint16_t f2bf(float x) {
    uint32_t u = __float_as_uint(x);
    return (uint16_t)((u + 0x7FFFu + ((u >> 16) & 1u)) >> 16);
}
__device__ __forceinline__ float bf2f(uint16_t s) {
    return __uint_as_float((uint32_t)s << 16);
}

// ---------------- pass 1: pack candidate B-fragments into d_ws --------------
// Per candidate two 16B entries (8 bf16 each), 32x32x16 B layout (R8-validated):
//   entry0 (k=0..7):  { c_hi.xyz, c_lo.xyz, 1.0, 1.0 }
//   entry1 (k=8..15): { c_hi.xyz, nc_hi, nc_lo, 0, 0, 0 }
// ws per batch: [entry0 n=0..8191][entry1 n=0..8191].  Also zeroes d_out.
__global__ __launch_bounds__(256) void pack_kernel(
    const float* __restrict__ xyz, uint4* __restrict__ ws,
    float* __restrict__ out, int total)
{
    int t = blockIdx.x * 256 + threadIdx.x;
    if (t == 0) *out = 0.0f;
    if (t >= total) return;
    int b = t >> 13;
    int n = t & (NPTS - 1);
    const float* p = xyz + ((size_t)b * NPTS + n) * 3;
    float cx = p[0], cy = p[1], cz = p[2];
    uint16_t bhx = f2bf(cx), bhy = f2bf(cy), bhz = f2bf(cz);
    uint16_t blx = f2bf(cx - bf2f(bhx));
    uint16_t bly = f2bf(cy - bf2f(bhy));
    uint16_t blz = f2bf(cz - bf2f(bhz));
    float nc = fmaf(cz, cz, fmaf(cy, cy, cx * cx));
    uint16_t nch = f2bf(nc), ncl = f2bf(nc - bf2f(nch));
    const uint32_t ONE = 0x3F80u;  // bf16(1.0)
    uint4 a0, a1;
    a0.x = (uint32_t)bhx | ((uint32_t)bhy << 16);
    a0.y = (uint32_t)bhz | ((uint32_t)blx << 16);
    a0.z = (uint32_t)bly | ((uint32_t)blz << 16);
    a0.w = ONE | (ONE << 16);
    a1.x = (uint32_t)bhx | ((uint32_t)bhy << 16);
    a1.y = (uint32_t)bhz | ((uint32_t)nch << 16);
    a1.z = (uint32_t)ncl;
    a1.w = 0u;
    size_t base = (size_t)b * (2 * NPTS);
    ws[base + n]        = a0;
    ws[base + NPTS + n] = a1;
}

// ---------------- pass 2: MFMA K-loop over HALF the candidates --------------
// d(m,n) = |c|^2+|q|^2+eps-2q.c via one 32x32x16 bf16 MFMA per 32 candidates.
// S=2 split: block (bb,grp,half) scans candidates [half*4096, half*4096+4096)
// for query group grp; writes the group's per-query partial top-3 packed keys
// to global scratch. Doubles block supply: 1024 blocks -> ~3 blocks/CU
// (gather tail removed -> lower VGPR). No __launch_bounds__ min-waves
// (R2/R6: allocator over-squeeze -> spills). Keys: high 19 bits = fp32 bits
// of distance (+eps>0), low 13 = candidate index.
__global__ __launch_bounds__(BLK) void knn_mfma_kernel(
    const float* __restrict__ xyz,
    const uint4* __restrict__ pk,
    uint32_t* __restrict__ halves)
{
    __shared__ uint32_t keybuf[QPB * 256];   // 32 KB
    const int tid  = threadIdx.x;
    const int lane = tid & 63;
    const int wv   = tid >> 6;
    const int qcol = lane & 31;     // MFMA col
    const int hl   = lane >> 5;     // k-half
    const int bb   = blockIdx.x / (GRPS * 2);
    const int rem  = blockIdx.x % (GRPS * 2);
    const int grp  = rem >> 1;
    const int half = rem & 1;
    const int qbase = grp * QPB;
    const float* xb = xyz + (size_t)bb * NPTS * 3;
    const uint4* pkb = pk + (size_t)bb * (2 * NPTS);

    // --- A fragment (queries; constant across tiles) — R8-validated layout ---
    const int qm = qbase + qcol;
    const float qx = xb[qm * 3 + 0], qy = xb[qm * 3 + 1], qz = xb[qm * 3 + 2];
    const float ax = -2.0f * qx, ay = -2.0f * qy, az = -2.0f * qz;
    const uint16_t ahx = f2bf(ax), ahy = f2bf(ay), ahz = f2bf(az);
    const uint16_t alx = f2bf(ax - bf2f(ahx));
    const uint16_t aly = f2bf(ay - bf2f(ahy));
    const uint16_t alz = f2bf(az - bf2f(ahz));
    const float nqe = fmaf(qz, qz, fmaf(qy, qy, qx * qx)) + 1e-3f;  // eps keeps self>0
    const uint16_t nqh = f2bf(nqe), nql = f2bf(nqe - bf2f(nqh));
    short8 A;
    if (hl == 0) {
        A[0] = (short)ahx; A[1] = (short)ahy; A[2] = (short)ahz;
        A[3] = (short)ahx; A[4] = (short)ahy; A[5] = (short)ahz;
        A[6] = (short)nqh; A[7] = (short)nql;
    } else {
        A[0] = (short)alx; A[1] = (short)aly; A[2] = (short)alz;
        A[3] = (short)0x3F80; A[4] = (short)0x3F80;  // 1.0 for the |c|^2 slots
        A[5] = 0; A[6] = 0; A[7] = 0;
    }
    const float16 Z = (float16)0.0f;

    // 16 running min keys — SCALARS ONLY (R3: arrays fall to scratch).
    uint32_t k0 = ~0u, k1 = ~0u, k2 = ~0u, k3 = ~0u, k4 = ~0u, k5 = ~0u, k6 = ~0u, k7 = ~0u;
    uint32_t k8 = ~0u, k9 = ~0u, k10 = ~0u, k11 = ~0u, k12 = ~0u, k13 = ~0u, k14 = ~0u, k15 = ~0u;

    // Barrier-free K-loop: 16 iterations over this block's 4096 candidates.
    const int nstart = half * 4096 + wv * 512;
    const short8* lanep = (const short8*)(pkb + (size_t)hl * NPTS + nstart + qcol);
    const uint32_t nb0 = (uint32_t)(nstart + qcol);
#pragma unroll 2
    for (int t = 0; t < 16; ++t) {
        short8 Bf = lanep[t * 32];
        float16 D = __builtin_amdgcn_mfma_f32_32x32x16_bf16(A, Bf, Z, 0, 0, 0);
        const uint32_t jj = nb0 + (uint32_t)(t * 32);
#define KU(i, ki) ki = umin32(ki, (__float_as_uint(D[i]) & 0xFFFFE000u) | jj)
        KU(0, k0);  KU(1, k1);  KU(2, k2);  KU(3, k3);
        KU(4, k4);  KU(5, k5);  KU(6, k6);  KU(7, k7);
        KU(8, k8);  KU(9, k9);  KU(10, k10); KU(11, k11);
        KU(12, k12); KU(13, k13); KU(14, k14); KU(15, k15);
#undef KU
    }

    // keybuf[row][256 bins]: reg r -> row (r&3)+8*(r>>2)+4*hl; col wv*32+qcol.
    {
        const int base = hl * 1024 + wv * 32 + qcol;   // word index (4 rows * 256)
        keybuf[base +    0] = k0;   keybuf[base +  256] = k1;
        keybuf[base +  512] = k2;   keybuf[base +  768] = k3;
        keybuf[base + 2048] = k4;   keybuf[base + 2304] = k5;
        keybuf[base + 2560] = k6;   keybuf[base + 2816] = k7;
        keybuf[base + 4096] = k8;   keybuf[base + 4352] = k9;
        keybuf[base + 4608] = k10;  keybuf[base + 4864] = k11;
        keybuf[base + 6144] = k12;  keybuf[base + 6400] = k13;
        keybuf[base + 6656] = k14;  keybuf[base + 6912] = k15;
    }
    __syncthreads();

    // merge: wave wv owns rows wv*4+g (g=lane>>4); 16 lanes scan 256 bins;
    // li==0 writes this half's top-3 keys for its row to global scratch.
    {
        const int g = lane >> 4, li = lane & 15;
        const int row = wv * 4 + g;
        uint32_t K0 = ~0u, K1 = ~0u, K2 = ~0u;
#pragma unroll
        for (int s = 0; s < 16; ++s) ins3(keybuf[row * 256 + li + s * 16], K0, K1, K2);
#pragma unroll
        for (int mk = 1; mk < 16; mk <<= 1) {
            uint32_t r0 = (uint32_t)__shfl_xor((int)K0, mk);
            uint32_t r1 = (uint32_t)__shfl_xor((int)K1, mk);
            uint32_t r2 = (uint32_t)__shfl_xor((int)K2, mk);
            ins3(r0, K0, K1, K2);
            ins3(r1, K0, K1, K2);
            ins3(r2, K0, K1, K2);
        }
        if (li == 0) {
            uint32_t* dst = halves + (size_t)blockIdx.x * (QPB * 3) + row * 3;
            dst[0] = K0;
            dst[1] = K1;
            dst[2] = K2;
        }
    }
}

// ---------------- pass 3: merge halves + gather + loss ----------------------
// Exact: each half's top-3 are its 3 smallest, so the global top-3 lie in the
// 6-key union. Lane c owns a channel: [0,4)=rot, [4,7)=sc, 7=op, [8,53)=col,
// 53=dist (exact fp32 recompute — bf16/eps never reach the output values).
__global__ __launch_bounds__(BLK) void finish_kernel(
    const float* __restrict__ xyz,
    const float* __restrict__ rot,
    const float* __restrict__ sc,
    const float* __restrict__ col,
    const float* __restrict__ opac,
    const uint32_t* __restrict__ halves,
    float* __restrict__ out,
    float inv_nb)
{
    __shared__ float blockAcc;
    const int tid  = threadIdx.x;
    const int lane = tid & 63;
    const int wv   = tid >> 6;
    const int bb   = blockIdx.x / GRPS;
    const int grp  = blockIdx.x % GRPS;
    const int qbase = grp * QPB;
    const float* xb = xyz + (size_t)bb * NPTS * 3;
    const size_t abase = (size_t)bb * NPTS;

    if (tid == 0) blockAcc = 0.0f;
    __syncthreads();

    const uint32_t* h0 = halves + (size_t)(blockIdx.x * 2 + 0) * (QPB * 3);
    const uint32_t* h1 = halves + (size_t)(blockIdx.x * 2 + 1) * (QPB * 3);

    float acc = 0.0f;
    for (int i = 0; i < 4; ++i) {
        const int q = wv * 4 + i;
        uint32_t K0 = ~0u, K1 = ~0u, K2 = ~0u;
        ins3(h0[q * 3 + 0], K0, K1, K2);
        ins3(h0[q * 3 + 1], K0, K1, K2);
        ins3(h0[q * 3 + 2], K0, K1, K2);
        ins3(h1[q * 3 + 0], K0, K1, K2);
        ins3(h1[q * 3 + 1], K0, K1, K2);
        ins3(h1[q * 3 + 2], K0, K1, K2);
        const int j0 = (int)(K0 & 8191u);
        const int j1 = (int)(K1 & 8191u);
        const int j2 = (int)(K2 & 8191u);
        const int qi = qbase + q;
        const float xp = xb[qi * 3 + 0], yp = xb[qi * 3 + 1], zp = xb[qi * 3 + 2];

        int c = lane;
        const float* basep = nullptr;
        int stridec = 0, ch = 0;
        float w = 0.0f;
        if (c < 4)       { basep = rot  + abase * 4;  stridec = 4;  ch = c;     w = inv_nb * (1.0f / 4.0f); }
        else if (c < 7)  { basep = sc   + abase * 3;  stridec = 3;  ch = c - 4; w = inv_nb * (1.0f / 3.0f); }
        else if (c == 7) { basep = opac + abase;      stridec = 1;  ch = 0;     w = inv_nb; }
        else if (c < 53) { basep = col  + abase * 45; stridec = 45; ch = c - 8; w = inv_nb * (1.0f / 45.0f); }

        if (basep != nullptr) {
            float v0 = basep[(size_t)j0 * stridec + ch];
            float v1 = basep[(size_t)j1 * stridec + ch];
            float v2 = basep[(size_t)j2 * stridec + ch];
            float mn = (v0 + v1 + v2) * (1.0f / 3.0f);
            float e0 = v0 - mn, e1 = v1 - mn, e2 = v2 - mn;
            acc += w * sqrtf((e0 * e0 + e1 * e1 + e2 * e2) * 0.5f);  // ddof=1
        } else if (c == 53) {
            float dx = xb[j0 * 3 + 0] - xp, dy = xb[j0 * 3 + 1] - yp, dz = xb[j0 * 3 + 2] - zp;
            float ds = fmaf(dz, dz, fmaf(dy, dy, dx * dx));
            dx = xb[j1 * 3 + 0] - xp; dy = xb[j1 * 3 + 1] - yp; dz = xb[j1 * 3 + 2] - zp;
            ds += fmaf(dz, dz, fmaf(dy, dy, dx * dx));
            dx = xb[j2 * 3 + 0] - xp; dy = xb[j2 * 3 + 1] - yp; dz = xb[j2 * 3 + 2] - zp;
            ds += fmaf(dz, dz, fmaf(dy, dy, dx * dx));
            acc += ds * (inv_nb * (1.0f / 3.0f));
        }
    }

#pragma unroll
    for (int off = 32; off > 0; off >>= 1) acc += __shfl_xor(acc, off);
    if (lane == 0) atomicAdd(&blockAcc, acc);
    __syncthreads();
    if (tid == 0) atomicAdd(out, blockAcc);
}

extern "C" void kernel_launch(void* const* d_in, const int* in_sizes, int n_in,
                              void* d_out, int out_size, void* d_ws, size_t ws_size,
                              hipStream_t stream) {
    const float* xyz  = (const float*)d_in[0];
    const float* rot  = (const float*)d_in[1];
    const float* sc   = (const float*)d_in[2];
    const float* colr = (const float*)d_in[3];
    const float* opac = (const float*)d_in[4];
    float* out = (float*)d_out;

    const int B = in_sizes[0] / (NPTS * 3);  // = 2
    const float inv_nb = 1.0f / ((float)NPTS * (float)B);
    const int total = B * NPTS;

    uint4* pk = (uint4*)d_ws;                              // B*2*8192*16B = 512 KB
    uint32_t* halves = (uint32_t*)((char*)d_ws + (1 << 20));  // 1 MB offset; B*256*2*96*4B = 384 KB

    // pack_kernel also zeroes d_out; d_ws regions fully rewritten each launch.
    pack_kernel<<<dim3((total + 255) / 256), dim3(256), 0, stream>>>(
        xyz, pk, out, total);
    knn_mfma_kernel<<<dim3(B * GRPS * 2), dim3(BLK), 0, stream>>>(
        xyz, (const uint4*)pk, halves);
    finish_kernel<<<dim3(B * GRPS), dim3(BLK), 0, stream>>>(
        xyz, rot, sc, colr, opac, (const uint32_t*)halves, out, inv_nb);
}

// Round 13
// 84.383 us; speedup vs baseline: 1.0785x; 1.0785x over previous
//
#include <hip/hip_runtime.h>
#include <stdint.h>

#define NPTS 8192
#define BLK 512                       // 8 waves
#define QPB 32                        // queries per block (one MFMA row-block)
#define BLKS_PER_BATCH (NPTS / QPB)   // 256 -> grid 512 (2 blocks/CU)

typedef __attribute__((ext_vector_type(8)))  short short8;
typedef __attribute__((ext_vector_type(16))) float float16;

__device__ __forceinline__ uint32_t umin32(uint32_t a, uint32_t b) { return a < b ? a : b; }
__device__ __forceinline__ uint32_t umax32(uint32_t a, uint32_t b) { return a > b ? a : b; }

__device__ __forceinline__ void ins3(uint32_t key, uint32_t& k0, uint32_t& k1, uint32_t& k2) {
    uint32_t a = umin32(k0, key);
    uint32_t b = umax32(k0, key);
    k0 = a;
    uint32_t c = umin32(k1, b);
    uint32_t d = umax32(k1, b);
    k1 = c;
    k2 = umin32(k2, d);
}

// RNE float->bf16 (bits in uint16) and back.
__device__ __forceinline__ uint16_t f2bf(float x) {
    uint32_t u = __float_as_uint(x);
    return (uint16_t)((u + 0x7FFFu + ((u >> 16) & 1u)) >> 16);
}
__device__ __forceinline__ float bf2f(uint16_t s) {
    return __uint_as_float((uint32_t)s << 16);
}

// ---------------- pass 1: pack candidate B-fragments into d_ws --------------
// Per candidate two 16B entries (8 bf16 each), 32x32x16 B layout (R8-validated):
//   entry0 (k=0..7):  { c_hi.xyz, c_lo.xyz, 1.0, 1.0 }
//   entry1 (k=8..15): { c_hi.xyz, nc_hi, nc_lo, 0, 0, 0 }
// ws per batch: [entry0 n=0..8191][entry1 n=0..8191].  Also zeroes d_out.
__global__ __launch_bounds__(256) void pack_kernel(
    const float* __restrict__ xyz, uint4* __restrict__ ws,
    float* __restrict__ out, int total)
{
    int t = blockIdx.x * 256 + threadIdx.x;
    if (t == 0) *out = 0.0f;
    if (t >= total) return;
    int b = t >> 13;
    int n = t & (NPTS - 1);
    const float* p = xyz + ((size_t)b * NPTS + n) * 3;
    float cx = p[0], cy = p[1], cz = p[2];
    uint16_t bhx = f2bf(cx), bhy = f2bf(cy), bhz = f2bf(cz);
    uint16_t blx = f2bf(cx - bf2f(bhx));
    uint16_t bly = f2bf(cy - bf2f(bhy));
    uint16_t blz = f2bf(cz - bf2f(bhz));
    float nc = fmaf(cz, cz, fmaf(cy, cy, cx * cx));
    uint16_t nch = f2bf(nc), ncl = f2bf(nc - bf2f(nch));
    const uint32_t ONE = 0x3F80u;  // bf16(1.0)
    uint4 a0, a1;
    a0.x = (uint32_t)bhx | ((uint32_t)bhy << 16);
    a0.y = (uint32_t)bhz | ((uint32_t)blx << 16);
    a0.z = (uint32_t)bly | ((uint32_t)blz << 16);
    a0.w = ONE | (ONE << 16);
    a1.x = (uint32_t)bhx | ((uint32_t)bhy << 16);
    a1.y = (uint32_t)bhz | ((uint32_t)nch << 16);
    a1.z = (uint32_t)ncl;
    a1.w = 0u;
    size_t base = (size_t)b * (2 * NPTS);
    ws[base + n]        = a0;
    ws[base + NPTS + n] = a1;
}

// Gather attributes for one query's top-3; lane c owns a channel:
// [0,4)=rot, [4,7)=sc, 7=op, [8,53)=col, 53=dist (exact fp32 recompute —
// bf16/eps approximations never reach the output values).
__device__ __forceinline__ float point_contrib(
    int j0, int j1, int j2,
    int lane, float xp, float yp, float zp,
    const float* __restrict__ xb,
    const float* __restrict__ rot, const float* __restrict__ sc,
    const float* __restrict__ col, const float* __restrict__ opac,
    size_t abase, float inv_nb)
{
    int c = lane;
    const float* basep = nullptr;
    int stridec = 0, ch = 0;
    float w = 0.0f;
    if (c < 4)       { basep = rot  + abase * 4;  stridec = 4;  ch = c;     w = inv_nb * (1.0f / 4.0f); }
    else if (c < 7)  { basep = sc   + abase * 3;  stridec = 3;  ch = c - 4; w = inv_nb * (1.0f / 3.0f); }
    else if (c == 7) { basep = opac + abase;      stridec = 1;  ch = 0;     w = inv_nb; }
    else if (c < 53) { basep = col  + abase * 45; stridec = 45; ch = c - 8; w = inv_nb * (1.0f / 45.0f); }

    if (basep != nullptr) {
        float v0 = basep[(size_t)j0 * stridec + ch];
        float v1 = basep[(size_t)j1 * stridec + ch];
        float v2 = basep[(size_t)j2 * stridec + ch];
        float mn = (v0 + v1 + v2) * (1.0f / 3.0f);
        float e0 = v0 - mn, e1 = v1 - mn, e2 = v2 - mn;
        return w * sqrtf((e0 * e0 + e1 * e1 + e2 * e2) * 0.5f);  // ddof=1
    }
    if (c == 53) {
        float dx = xb[j0 * 3 + 0] - xp, dy = xb[j0 * 3 + 1] - yp, dz = xb[j0 * 3 + 2] - zp;
        float ds = fmaf(dz, dz, fmaf(dy, dy, dx * dx));
        dx = xb[j1 * 3 + 0] - xp; dy = xb[j1 * 3 + 1] - yp; dz = xb[j1 * 3 + 2] - zp;
        ds += fmaf(dz, dz, fmaf(dy, dy, dx * dx));
        dx = xb[j2 * 3 + 0] - xp; dy = xb[j2 * 3 + 1] - yp; dz = xb[j2 * 3 + 2] - zp;
        ds += fmaf(dz, dz, fmaf(dy, dy, dx * dx));
        return ds * (inv_nb * (1.0f / 3.0f));
    }
    return 0.0f;
}

// ---------------- pass 2: barrier-free MFMA K-loop ------------------------
// d(m,n) = |c|^2+|q|^2+eps-2q.c via one 32x32x16 bf16 MFMA per 32 candidates.
// B-fragments read DIRECTLY from global (L2-resident 512 KB/batch) — no LDS
// staging, no __syncthreads in the K-loop. Wave wv scans candidates
// [wv*1024, wv*1024+1024); bins are (wave,qcol) columns of the keybuf.
// No __launch_bounds__ min-waves (R2/R6: allocator over-squeeze -> spills).
__global__ __launch_bounds__(BLK) void knn_mfma_kernel(
    const float* __restrict__ xyz,
    const float* __restrict__ rot,
    const float* __restrict__ sc,
    const float* __restrict__ colr,
    const float* __restrict__ opac,
    const uint4* __restrict__ pk,
    float* __restrict__ out,
    float inv_nb)
{
    __shared__ uint32_t keybuf[QPB * 256];   // 32 KB
    __shared__ int top3j[QPB * 3];
    __shared__ float blockAcc;

    const int tid  = threadIdx.x;
    const int lane = tid & 63;
    const int wv   = tid >> 6;
    const int qcol = lane & 31;     // MFMA col (candidate within 32-tile)
    const int hl   = lane >> 5;     // k-half
    const int bb   = blockIdx.x / BLKS_PER_BATCH;
    const int qbase = (blockIdx.x % BLKS_PER_BATCH) * QPB;
    const float* xb = xyz + (size_t)bb * NPTS * 3;
    const uint4* pkb = pk + (size_t)bb * (2 * NPTS);

    if (tid == 0) blockAcc = 0.0f;

    // --- A fragment (queries; constant across all tiles) — R8/R9-validated ---
    const int qm = qbase + qcol;
    const float qx = xb[qm * 3 + 0], qy = xb[qm * 3 + 1], qz = xb[qm * 3 + 2];
    const float ax = -2.0f * qx, ay = -2.0f * qy, az = -2.0f * qz;
    const uint16_t ahx = f2bf(ax), ahy = f2bf(ay), ahz = f2bf(az);
    const uint16_t alx = f2bf(ax - bf2f(ahx));
    const uint16_t aly = f2bf(ay - bf2f(ahy));
    const uint16_t alz = f2bf(az - bf2f(ahz));
    const float nqe = fmaf(qz, qz, fmaf(qy, qy, qx * qx)) + 1e-3f;  // eps keeps self>0
    const uint16_t nqh = f2bf(nqe), nql = f2bf(nqe - bf2f(nqh));
    short8 A;
    if (hl == 0) {
        A[0] = (short)ahx; A[1] = (short)ahy; A[2] = (short)ahz;
        A[3] = (short)ahx; A[4] = (short)ahy; A[5] = (short)ahz;
        A[6] = (short)nqh; A[7] = (short)nql;
    } else {
        A[0] = (short)alx; A[1] = (short)aly; A[2] = (short)alz;
        A[3] = (short)0x3F80; A[4] = (short)0x3F80;  // 1.0 for the |c|^2 slots
        A[5] = 0; A[6] = 0; A[7] = 0;
    }
    const float16 Z = (float16)0.0f;

    // 16 running min keys — SCALARS ONLY (R3: arrays fall to scratch).
    uint32_t k0 = ~0u, k1 = ~0u, k2 = ~0u, k3 = ~0u, k4 = ~0u, k5 = ~0u, k6 = ~0u, k7 = ~0u;
    uint32_t k8 = ~0u, k9 = ~0u, k10 = ~0u, k11 = ~0u, k12 = ~0u, k13 = ~0u, k14 = ~0u, k15 = ~0u;

    // Barrier-free K-loop: lane's B-frag pointer; 32 independent iterations.
    const int nstart = wv * 1024;
    const uint4* lanep = pkb + (size_t)hl * NPTS + nstart + qcol;
    const uint32_t nb0 = (uint32_t)(nstart + qcol);
#pragma unroll 4
    for (int t = 0; t < 32; ++t) {
        uint4 wrd = lanep[t * 32];
        short8 Bf;
        Bf[0] = (short)(wrd.x & 0xFFFFu); Bf[1] = (short)(wrd.x >> 16);
        Bf[2] = (short)(wrd.y & 0xFFFFu); Bf[3] = (short)(wrd.y >> 16);
        Bf[4] = (short)(wrd.z & 0xFFFFu); Bf[5] = (short)(wrd.z >> 16);
        Bf[6] = (short)(wrd.w & 0xFFFFu); Bf[7] = (short)(wrd.w >> 16);
        float16 D = __builtin_amdgcn_mfma_f32_32x32x16_bf16(A, Bf, Z, 0, 0, 0);
        const uint32_t jj = nb0 + (uint32_t)(t * 32);
#define KU(i, ki) ki = umin32(ki, (__float_as_uint(D[i]) & 0xFFFFE000u) | jj)
        KU(0, k0);  KU(1, k1);  KU(2, k2);  KU(3, k3);
        KU(4, k4);  KU(5, k5);  KU(6, k6);  KU(7, k7);
        KU(8, k8);  KU(9, k9);  KU(10, k10); KU(11, k11);
        KU(12, k12); KU(13, k13); KU(14, k14); KU(15, k15);
#undef KU
    }

    // keybuf[row][256 bins]: reg r -> row (r&3)+8*(r>>2)+4*hl; col wv*32+qcol.
    {
        const int base = hl * 1024 + wv * 32 + qcol;   // word index (4 rows * 256)
        keybuf[base +    0] = k0;   keybuf[base +  256] = k1;
        keybuf[base +  512] = k2;   keybuf[base +  768] = k3;
        keybuf[base + 2048] = k4;   keybuf[base + 2304] = k5;
        keybuf[base + 2560] = k6;   keybuf[base + 2816] = k7;
        keybuf[base + 4096] = k8;   keybuf[base + 4352] = k9;
        keybuf[base + 4608] = k10;  keybuf[base + 4864] = k11;
        keybuf[base + 6144] = k12;  keybuf[base + 6400] = k13;
        keybuf[base + 6656] = k14;  keybuf[base + 6912] = k15;
    }
    __syncthreads();

    // merge: wave wv owns rows wv*4+g (g=lane>>4); 16 lanes scan 256 bins.
    {
        const int g = lane >> 4, li = lane & 15;
        const int row = wv * 4 + g;
        uint32_t K0 = ~0u, K1 = ~0u, K2 = ~0u;
#pragma unroll
        for (int s = 0; s < 16; ++s) ins3(keybuf[row * 256 + li + s * 16], K0, K1, K2);
#pragma unroll
        for (int mk = 1; mk < 16; mk <<= 1) {
            uint32_t r0 = (uint32_t)__shfl_xor((int)K0, mk);
            uint32_t r1 = (uint32_t)__shfl_xor((int)K1, mk);
            uint32_t r2 = (uint32_t)__shfl_xor((int)K2, mk);
            ins3(r0, K0, K1, K2);
            ins3(r1, K0, K1, K2);
            ins3(r2, K0, K1, K2);
        }
        if (li == 0) {
            top3j[row * 3 + 0] = (int)(K0 & 8191u);
            top3j[row * 3 + 1] = (int)(K1 & 8191u);
            top3j[row * 3 + 2] = (int)(K2 & 8191u);
        }
    }
    __syncthreads();

    // gather: wave wv handles queries wv*4 .. wv*4+3
    float acc = 0.0f;
    const size_t abase = (size_t)bb * NPTS;
    for (int i = 0; i < 4; ++i) {
        const int q = wv * 4 + i;
        const int j0 = top3j[q * 3 + 0];
        const int j1 = top3j[q * 3 + 1];
        const int j2 = top3j[q * 3 + 2];
        const int qi = qbase + q;
        const float xp = xb[qi * 3 + 0], yp = xb[qi * 3 + 1], zp = xb[qi * 3 + 2];
        acc += point_contrib(j0, j1, j2, lane, xp, yp, zp,
                             xb, rot, sc, colr, opac, abase, inv_nb);
    }

#pragma unroll
    for (int off = 32; off > 0; off >>= 1) acc += __shfl_xor(acc, off);
    if (lane == 0) atomicAdd(&blockAcc, acc);
    __syncthreads();
    if (tid == 0) atomicAdd(out, blockAcc);
}

extern "C" void kernel_launch(void* const* d_in, const int* in_sizes, int n_in,
                              void* d_out, int out_size, void* d_ws, size_t ws_size,
                              hipStream_t stream) {
    const float* xyz  = (const float*)d_in[0];
    const float* rot  = (const float*)d_in[1];
    const float* sc   = (const float*)d_in[2];
    const float* colr = (const float*)d_in[3];
    const float* opac = (const float*)d_in[4];
    float* out = (float*)d_out;

    const int B = in_sizes[0] / (NPTS * 3);  // = 2
    const float inv_nb = 1.0f / ((float)NPTS * (float)B);
    const int total = B * NPTS;

    // pack_kernel also zeroes d_out (stream-ordered before the main kernel);
    // d_ws is fully rewritten each launch (re-poison safe).
    pack_kernel<<<dim3((total + 255) / 256), dim3(256), 0, stream>>>(
        xyz, (uint4*)d_ws, out, total);
    knn_mfma_kernel<<<dim3(B * BLKS_PER_BATCH), dim3(BLK), 0, stream>>>(
        xyz, rot, sc, colr, opac, (const uint4*)d_ws, out, inv_nb);
}